// Round 8
// baseline (349.004 us; speedup 1.0000x reference)
//
#include <hip/hip_runtime.h>
#include <math.h>

// SplineConv x2 (K=4, dim=1, degree=1, mean aggr) + ELU + log_softmax.
// R8: R7's channel-sharding achieved L2-residency (FETCH 104->34MB) but
// tripled L1 transactions (16B gathers, 4x edge work) -> slower. Fix:
// shard by SRC-QUARTILE instead. Edges per node sorted by src quartile
// (1024-bin counting sort); wave (node,qt) reads only quartile qt's table
// slice (src-major layout -> contiguous 3.2MB, pinned via blockIdx&3 to
// XCDs). Each edge processed ONCE with full 64B row gathers. Quartile
// partials combined by atomicAdd into zeroed fp32 accumulators; finalize
// kernels do mean+root+bias+ELU / log_softmax.

#define F_IN   48
#define HID    32
#define NCLS   10
#define KS     4
#define BKT_SH 8               // 256 nodes per bucket
#define TILE   4096            // edges per bucket_scatter block

__device__ inline unsigned short f2bf(float f) {
    unsigned x = __float_as_uint(f);
    unsigned r = x + 0x7FFFu + ((x >> 16) & 1u);  // RNE
    return (unsigned short)(r >> 16);
}
__device__ inline float bf2f(unsigned short u) {
    return __uint_as_float(((unsigned)u) << 16);
}

// ---------- CSR build ----------

__global__ void bucket_hist_kernel(const int* __restrict__ ei, int* __restrict__ bcnt,
                                   int E, int NB) {
    __shared__ int lcnt[256];
    int t = threadIdx.x;
    lcnt[t] = 0;
    __syncthreads();
    int e0 = blockIdx.x * TILE;
    int n = min(TILE, E - e0);
    for (int r = 0; r < TILE / 256; ++r) {
        int i = r * 256 + t;
        if (i < n) atomicAdd(&lcnt[ei[E + e0 + i] >> BKT_SH], 1);
    }
    __syncthreads();
    if (t < NB && lcnt[t] > 0) atomicAdd(&bcnt[t], lcnt[t]);
}

__global__ void mini_scan_kernel(const int* __restrict__ bcnt, int* __restrict__ bbase,
                                 int* __restrict__ gcur, int NB) {
    __shared__ int a[256], c[256];
    int t = threadIdx.x;
    int v = (t < NB) ? bcnt[t] : 0;
    a[t] = v; c[t] = v;
    __syncthreads();
    for (int o = 1; o < 256; o <<= 1) {
        int w = (t >= o) ? a[t - o] : 0;
        __syncthreads();
        a[t] += w;
        __syncthreads();
    }
    int ex = a[t] - c[t];
    if (t < NB) { bbase[t] = ex; gcur[t] = ex; }
    if (t == 0) bbase[NB] = a[255];
}

__global__ void bucket_scatter_kernel(const int* __restrict__ ei, const float* __restrict__ ea,
                                      int* __restrict__ gcur, uint2* __restrict__ tpd,
                                      int E, int NB) {
    __shared__ unsigned spl[TILE];
    __shared__ unsigned short sdst[TILE];
    __shared__ unsigned short inv[TILE];
    __shared__ int lcnt[256], loff[256], lrank[256], gb[256];
    int t = threadIdx.x;
    lcnt[t] = 0; lrank[t] = 0;
    __syncthreads();
    int e0 = blockIdx.x * TILE;
    int n = min(TILE, E - e0);
    for (int r = 0; r < TILE / 256; ++r) {
        int i = r * 256 + t;
        if (i < n) {
            int e = e0 + i;
            int src = ei[e];
            int dst = ei[E + e];
            float u = ea[e];
            float v = u * (float)(KS - 1);
            float vf = floorf(v);
            int k0 = min(max((int)vf, 0), KS - 1);
            unsigned qf = (unsigned)((v - vf) * 16383.f + 0.5f);  // 14-bit frac
            spl[i] = ((unsigned)src << 2) | (unsigned)k0 | (qf << 18);  // srck | frac
            sdst[i] = (unsigned short)dst;
            atomicAdd(&lcnt[dst >> BKT_SH], 1);
        }
    }
    __syncthreads();
    loff[t] = lcnt[t];
    __syncthreads();
    for (int o = 1; o < 256; o <<= 1) {
        int w = (t >= o) ? loff[t - o] : 0;
        __syncthreads();
        loff[t] += w;
        __syncthreads();
    }
    int ex = loff[t] - lcnt[t];
    __syncthreads();
    loff[t] = ex;
    if (t < NB) gb[t] = atomicAdd(&gcur[t], lcnt[t]);
    __syncthreads();
    for (int r = 0; r < TILE / 256; ++r) {
        int i = r * 256 + t;
        if (i < n) {
            int b = sdst[i] >> BKT_SH;
            int p = loff[b] + atomicAdd(&lrank[b], 1);
            inv[p] = (unsigned short)i;
        }
    }
    __syncthreads();
    for (int r = 0; r < TILE / 256; ++r) {
        int j = r * 256 + t;
        if (j < n) {
            int i = inv[j];
            int d = sdst[i];
            int b = d >> BKT_SH;
            int pos = gb[b] + (j - loff[b]);
            tpd[pos] = make_uint2(spl[i], (unsigned)d);
        }
    }
}

// One block per bucket: sort by (dst_local, src_quartile) -> 1024 bins.
// Emits spk (quartile-grouped per node) and offs4[4N+1].
__global__ void node_sort_kernel(const uint2* __restrict__ tpd, const int* __restrict__ bbase,
                                 unsigned* __restrict__ spk, int* __restrict__ offs4,
                                 int N, int NB, int Q) {
    __shared__ int hc[1024], hs[1024], hr[1024], part[256];
    int b = blockIdx.x;
    int t = threadIdx.x;
    int nb0 = b << BKT_SH;
    int nb = min(256, N - nb0);
    int base = bbase[b];
    int m = bbase[b + 1] - base;
    for (int j = t; j < 1024; j += 256) { hc[j] = 0; hr[j] = 0; }
    __syncthreads();
    for (int i = t; i < m; i += 256) {
        uint2 r = tpd[base + i];
        int d = r.y - nb0;
        int src = (r.x >> 2) & 0xFFFF;
        int qt = (src >= Q) + (src >= 2 * Q) + (src >= 3 * Q);
        atomicAdd(&hc[(d << 2) | qt], 1);
    }
    __syncthreads();
    int s = hc[4 * t] + hc[4 * t + 1] + hc[4 * t + 2] + hc[4 * t + 3];
    part[t] = s;
    __syncthreads();
    for (int o = 1; o < 256; o <<= 1) {
        int w = (t >= o) ? part[t - o] : 0;
        __syncthreads();
        part[t] += w;
        __syncthreads();
    }
    int run = part[t] - s;
#pragma unroll
    for (int j = 0; j < 4; ++j) { hs[4 * t + j] = run; run += hc[4 * t + j]; }
    __syncthreads();
    for (int j = t; j < 4 * nb; j += 256) offs4[(nb0 << 2) + j] = base + hs[j];
    if (b == NB - 1 && t == 0) offs4[4 * N] = base + m;
    for (int i = t; i < m; i += 256) {
        uint2 r = tpd[base + i];
        int d = r.y - nb0;
        int src = (r.x >> 2) & 0xFFFF;
        int qt = (src >= Q) + (src >= 2 * Q) + (src >= 3 * Q);
        int bin = (d << 2) | qt;
        int p = hs[bin] + atomicAdd(&hr[bin], 1);
        spk[base + p] = r.x;
    }
}

// ---------- xw tables (LDS-staged W, register-blocked) ----------

// outk[node][k][32c] bf16 (64B rows, src-major -> quartile = contiguous
// 3.2MB); outr[node][32c] fp32.
__global__ __launch_bounds__(320) void xw1_kernel(
        const float* __restrict__ X, const float* __restrict__ W,
        const float* __restrict__ R, unsigned short* __restrict__ outk,
        float* __restrict__ outr, int n) {
    __shared__ float lw[48 * 160];
    int t = threadIdx.x;
    for (int i = t; i < 48 * 160; i += 320) {
        int f = i / 160;
        int col = i - f * 160;
        lw[i] = (col < 128) ? W[(size_t)(col >> 5) * (48 * 32) + f * 32 + (col & 31)]
                            : R[f * 32 + (col - 128)];
    }
    __syncthreads();
    int g = t % 40;      // colgroup (4 cols)
    int lp = t / 40;     // local pair 0..7
    int n0 = (blockIdx.x * 8 + lp) * 2;
    if (n0 + 1 >= n) return;
    const float4* X0 = (const float4*)(X + (size_t)n0 * F_IN);
    const float4* X1 = (const float4*)(X + (size_t)(n0 + 1) * F_IN);
    float4 x0[12], x1[12];
#pragma unroll
    for (int i = 0; i < 12; ++i) { x0[i] = X0[i]; x1[i] = X1[i]; }
    const float4* lw4 = (const float4*)lw;  // lw4[f*40 + g]
    float4 a0 = {0,0,0,0}, a1 = {0,0,0,0};
#pragma unroll
    for (int fb = 0; fb < 12; ++fb) {
        float4 v0 = x0[fb], v1 = x1[fb];
#pragma unroll
        for (int j = 0; j < 4; ++j) {
            float s0 = (j == 0) ? v0.x : (j == 1) ? v0.y : (j == 2) ? v0.z : v0.w;
            float s1 = (j == 0) ? v1.x : (j == 1) ? v1.y : (j == 2) ? v1.z : v1.w;
            float4 w = lw4[(fb * 4 + j) * 40 + g];
            a0.x = fmaf(s0, w.x, a0.x); a0.y = fmaf(s0, w.y, a0.y);
            a0.z = fmaf(s0, w.z, a0.z); a0.w = fmaf(s0, w.w, a0.w);
            a1.x = fmaf(s1, w.x, a1.x); a1.y = fmaf(s1, w.y, a1.y);
            a1.z = fmaf(s1, w.z, a1.z); a1.w = fmaf(s1, w.w, a1.w);
        }
    }
    if (g < 32) {
        uint2 u0, u1;
        u0.x = f2bf(a0.x) | ((unsigned)f2bf(a0.y) << 16);
        u0.y = f2bf(a0.z) | ((unsigned)f2bf(a0.w) << 16);
        u1.x = f2bf(a1.x) | ((unsigned)f2bf(a1.y) << 16);
        u1.y = f2bf(a1.z) | ((unsigned)f2bf(a1.w) << 16);
        *(uint2*)(outk + (size_t)n0 * (KS * HID) + g * 4) = u0;
        *(uint2*)(outk + (size_t)(n0 + 1) * (KS * HID) + g * 4) = u1;
    } else {
        int o = 4 * g - 128;
        *(float4*)(outr + (size_t)n0 * HID + o) = a0;
        *(float4*)(outr + (size_t)(n0 + 1) * HID + o) = a1;
    }
}

// outk[node][k][16c] bf16 (32B rows, cols 10..15 pad, never consumed);
// outr[node][10] fp32.
__global__ void xw2_kernel(const float* __restrict__ H, const float* __restrict__ W,
                           const float* __restrict__ R, unsigned short* __restrict__ outk,
                           float* __restrict__ outr, int n) {
    __shared__ float lw2[32 * 50];
    int t = threadIdx.x;
    for (int i = t; i < 32 * 50; i += 256) {
        int f = i / 50;
        int col = i - f * 50;
        lw2[i] = (col < 40) ? W[(size_t)(col / 10) * (32 * 10) + f * 10 + (col % 10)]
                            : R[f * 10 + (col - 40)];
    }
    __syncthreads();
    int total = (n / 2) * 25;
    int id = blockIdx.x * blockDim.x + t;
    if (id >= total) return;
    int p = id % 25;
    int pr = id / 25;
    int n0 = 2 * pr;
    const float4* H0 = (const float4*)(H + (size_t)n0 * HID);
    const float4* H1 = (const float4*)(H + (size_t)(n0 + 1) * HID);
    float4 h0[8], h1[8];
#pragma unroll
    for (int i = 0; i < 8; ++i) { h0[i] = H0[i]; h1[i] = H1[i]; }
    const float2* lwp = (const float2*)lw2;  // lwp[f*25 + p]
    float ax0 = 0.f, ay0 = 0.f, ax1 = 0.f, ay1 = 0.f;
#pragma unroll
    for (int fb = 0; fb < 8; ++fb) {
        float4 v0 = h0[fb], v1 = h1[fb];
#pragma unroll
        for (int j = 0; j < 4; ++j) {
            float s0 = (j == 0) ? v0.x : (j == 1) ? v0.y : (j == 2) ? v0.z : v0.w;
            float s1 = (j == 0) ? v1.x : (j == 1) ? v1.y : (j == 2) ? v1.z : v1.w;
            float2 w = lwp[(fb * 4 + j) * 25 + p];
            ax0 = fmaf(s0, w.x, ax0); ay0 = fmaf(s0, w.y, ay0);
            ax1 = fmaf(s1, w.x, ax1); ay1 = fmaf(s1, w.y, ay1);
        }
    }
    int col = 2 * p;
    if (col < 40) {           // col = k*10+o; 10 even -> pair never straddles k
        int k = col / 10;
        int o = col - k * 10;
        *(unsigned*)(outk + (size_t)n0 * 64 + k * 16 + o) =
            f2bf(ax0) | ((unsigned)f2bf(ay0) << 16);
        *(unsigned*)(outk + (size_t)(n0 + 1) * 64 + k * 16 + o) =
            f2bf(ax1) | ((unsigned)f2bf(ay1) << 16);
    } else {
        int o = col - 40;
        *(float2*)(outr + (size_t)n0 * NCLS + o) = make_float2(ax0, ay0);
        *(float2*)(outr + (size_t)(n0 + 1) * NCLS + o) = make_float2(ax1, ay1);
    }
}

// ---------- aggregation (src-quartile sharded, full-row gathers) ----------

__device__ inline float g32(const unsigned short* __restrict__ tbl, unsigned p) {
    unsigned sk = p & 0x3FFFFu;           // src*4 + k0 ; row = 32 ushorts
    float fr = (float)(p >> 18) * (1.f / 16383.f);
    float v0 = bf2f(tbl[sk * 32]);
    float v1 = bf2f(tbl[sk * 32 + 32]);   // k0+1 row (k0<=2 always)
    return fmaf(fr, v1 - v0, v0);
}

// Block = 4 waves = 4 nodes, one quartile (blockIdx&3 -> XCD-pinned).
// Wave: 2 edge-slots x 32 ch, each slot unrolled 2x (4 edges in flight).
__global__ void agg1_kernel(const unsigned short* __restrict__ xwk,
                            const int* __restrict__ offs4, const unsigned* __restrict__ spk,
                            float* __restrict__ hacc, int n) {
    int lane = threadIdx.x & 63;
    int c = lane & 31;
    int slot = lane >> 5;
    int qt = blockIdx.x & 3;
    int node = (blockIdx.x >> 2) * 4 + (threadIdx.x >> 6);
    if (node >= n) return;
    int beg = offs4[node * 4 + qt], end = offs4[node * 4 + qt + 1];
    if (beg == end) return;
    const unsigned short* tbl = xwk + c;
    float s0 = 0.f, s1 = 0.f;
    int e = beg + slot;
    for (; e + 2 < end; e += 4) {
        unsigned p0 = __builtin_nontemporal_load(spk + e);
        unsigned p1 = __builtin_nontemporal_load(spk + e + 2);
        s0 += g32(tbl, p0);
        s1 += g32(tbl, p1);
    }
    if (e < end) s0 += g32(tbl, __builtin_nontemporal_load(spk + e));
    float sum = s0 + s1;
    sum += __shfl_xor(sum, 32, 64);
    if (slot == 0) atomicAdd(&hacc[(size_t)node * HID + c], sum);
}

__global__ void fin1_kernel(const float* __restrict__ hacc, const float* __restrict__ xr,
                            const int* __restrict__ offs4, const float* __restrict__ bias,
                            float* __restrict__ h, int n) {
    int id = blockIdx.x * 256 + threadIdx.x;
    if (id >= n * HID) return;
    int node = id >> 5, c = id & 31;
    int deg = offs4[node * 4 + 4] - offs4[node * 4];
    float m = hacc[id] / (float)(deg > 0 ? deg : 1);
    float o = m + xr[id] + bias[c];
    h[id] = (o > 0.f) ? o : expm1f(o);
}

__device__ inline float g16(const unsigned short* __restrict__ tbl, unsigned p) {
    unsigned sk = p & 0x3FFFFu;           // row = 16 ushorts
    float fr = (float)(p >> 18) * (1.f / 16383.f);
    float v0 = bf2f(tbl[sk * 16]);
    float v1 = bf2f(tbl[sk * 16 + 16]);
    return fmaf(fr, v1 - v0, v0);
}

// Wave: 4 edge-slots x 16 ch, unrolled 2x (8 edges in flight).
__global__ void agg2_kernel(const unsigned short* __restrict__ xwk,
                            const int* __restrict__ offs4, const unsigned* __restrict__ spk,
                            float* __restrict__ lacc, int n) {
    int lane = threadIdx.x & 63;
    int c = lane & 15;
    int slot = lane >> 4;
    int qt = blockIdx.x & 3;
    int node = (blockIdx.x >> 2) * 4 + (threadIdx.x >> 6);
    if (node >= n) return;
    int beg = offs4[node * 4 + qt], end = offs4[node * 4 + qt + 1];
    if (beg == end) return;
    const unsigned short* tbl = xwk + c;
    float s0 = 0.f, s1 = 0.f;
    int e = beg + slot;
    for (; e + 4 < end; e += 8) {
        unsigned p0 = __builtin_nontemporal_load(spk + e);
        unsigned p1 = __builtin_nontemporal_load(spk + e + 4);
        s0 += g16(tbl, p0);
        s1 += g16(tbl, p1);
    }
    if (e < end) s0 += g16(tbl, __builtin_nontemporal_load(spk + e));
    float sum = s0 + s1;
    sum += __shfl_xor(sum, 16, 64);
    sum += __shfl_xor(sum, 32, 64);
    if (lane < 16) atomicAdd(&lacc[(size_t)node * 16 + c], sum);
}

__global__ void fin2_kernel(const float* __restrict__ lacc, const float* __restrict__ xr,
                            const int* __restrict__ offs4, const float* __restrict__ bias,
                            float* __restrict__ out, int n) {
    int i = blockIdx.x * 256 + threadIdx.x;
    if (i >= n) return;
    int deg = offs4[i * 4 + 4] - offs4[i * 4];
    float inv = 1.f / (float)(deg > 0 ? deg : 1);
    const float* l0 = lacc + (size_t)i * 16;
    float4 a = *(const float4*)l0;
    float4 b = *(const float4*)(l0 + 4);
    float2 cpair = *(const float2*)(l0 + 8);
    float v[10] = {a.x, a.y, a.z, a.w, b.x, b.y, b.z, b.w, cpair.x, cpair.y};
    const float* rr = xr + (size_t)i * NCLS;
#pragma unroll
    for (int j = 0; j < 10; ++j) v[j] = v[j] * inv + rr[j] + bias[j];
    float mx = v[0];
#pragma unroll
    for (int j = 1; j < 10; ++j) mx = fmaxf(mx, v[j]);
    float s = 0.f;
#pragma unroll
    for (int j = 0; j < 10; ++j) s += expf(v[j] - mx);
    float ls = logf(s) + mx;
    float* o = out + (size_t)i * 10;
#pragma unroll
    for (int j = 0; j < 10; ++j) o[j] = v[j] - ls;
}

extern "C" void kernel_launch(void* const* d_in, const int* in_sizes, int n_in,
                              void* d_out, int out_size, void* d_ws, size_t ws_size,
                              hipStream_t stream) {
    const float* x       = (const float*)d_in[0];
    const int*   ei      = (const int*)d_in[1];
    const float* ea      = (const float*)d_in[2];
    const float* W1      = (const float*)d_in[3];
    const float* root1   = (const float*)d_in[4];
    const float* bias1   = (const float*)d_in[5];
    const float* W2      = (const float*)d_in[6];
    const float* root2   = (const float*)d_in[7];
    const float* bias2   = (const float*)d_in[8];
    float* out = (float*)d_out;

    const int N = in_sizes[0] / F_IN;      // 50000
    const int E = in_sizes[2];             // 1600000
    const int NB = (N + 255) >> BKT_SH;    // 196
    const int Q  = (N + 3) / 4;            // src-quartile width (12500)

    char* base = (char*)d_ws;
    size_t off = 0;
    auto alloc = [&](size_t bytes) {
        char* p = base + off;
        off = (off + bytes + 255) & ~(size_t)255;
        return (void*)p;
    };
    unsigned short* xwk1 = (unsigned short*)alloc((size_t)N * 128 * 2);  // 12.8 MB
    float* xr1           = (float*)alloc((size_t)N * HID * 4);           // 6.4 MB
    float* h             = (float*)alloc((size_t)N * HID * 4);           // 6.4 MB
    float* hacc          = (float*)alloc((size_t)N * HID * 4);           // 6.4 MB
    float* lacc          = (float*)alloc((size_t)N * 16 * 4);            // 3.2 MB
    float* xr2           = (float*)alloc((size_t)N * NCLS * 4);          // 2.0 MB
    int* offs4           = (int*)alloc(((size_t)4 * N + 1) * 4);         // 0.8 MB
    int* bcnt            = (int*)alloc((size_t)NB * 4);
    int* bbase           = (int*)alloc(((size_t)NB + 1) * 4);
    int* gcur            = (int*)alloc((size_t)NB * 4);
    unsigned* spk        = (unsigned*)alloc((size_t)E * 4);              // 6.4 MB
    uint2* tpd           = (uint2*)xwk1;   // E*8 = 12.8MB (dead before xw1)
    unsigned short* xwk2 = xwk1;           // N*64 ushorts, aliases layer-1
    if (ws_size < off) return;

    int ebk = (E + TILE - 1) / TILE;

    hipMemsetAsync(bcnt, 0, (size_t)NB * 4, stream);
    hipMemsetAsync(hacc, 0, (size_t)N * HID * 4, stream);
    hipMemsetAsync(lacc, 0, (size_t)N * 16 * 4, stream);
    bucket_hist_kernel<<<ebk, 256, 0, stream>>>(ei, bcnt, E, NB);
    mini_scan_kernel<<<1, 256, 0, stream>>>(bcnt, bbase, gcur, NB);
    bucket_scatter_kernel<<<ebk, 256, 0, stream>>>(ei, ea, gcur, tpd, E, NB);
    node_sort_kernel<<<NB, 256, 0, stream>>>(tpd, bbase, spk, offs4, N, NB, Q);
    // xw1 after node_sort (tpd aliases xwk1)
    xw1_kernel<<<(N + 15) / 16, 320, 0, stream>>>(x, W1, root1, xwk1, xr1, N);
    agg1_kernel<<<((N + 3) / 4) * 4, 256, 0, stream>>>(xwk1, offs4, spk, hacc, N);
    fin1_kernel<<<(N * HID + 255) / 256, 256, 0, stream>>>(hacc, xr1, offs4, bias1, h, N);
    {
        int total = (N / 2) * 25;
        xw2_kernel<<<(total + 255) / 256, 256, 0, stream>>>(h, W2, root2, xwk2, xr2, N);
    }
    agg2_kernel<<<((N + 3) / 4) * 4, 256, 0, stream>>>(xwk2, offs4, spk, lacc, N);
    fin2_kernel<<<(N + 255) / 256, 256, 0, stream>>>(lacc, xr2, offs4, bias2, out, N);
}

// Round 9
// 346.471 us; speedup vs baseline: 1.0073x; 1.0073x over previous
//
#include <hip/hip_runtime.h>
#include <math.h>

// SplineConv x2 (K=4, dim=1, degree=1, mean aggr) + ELU + log_softmax.
// R9: R8's src-quartile sharding achieved L2 residency (FETCH 104->32MB)
// but lost it all to 6.4M device-scope atomicAdds (WRITE_SIZE 25MB) and
// empty-segment memset plumbing. This round: each (node,quartile) wave
// writes its partial sum as a plain coalesced 128B store into a private
// buffer hacc4[qt][node][ch] (unconditional -> no memsets); fin kernels
// sum the 4 partials streaming. CSR build, quartile sort, xw kernels and
// XCD pinning (blockIdx&3 with round-robin block->XCD) unchanged.

#define F_IN   48
#define HID    32
#define NCLS   10
#define KS     4
#define BKT_SH 8               // 256 nodes per bucket
#define TILE   4096            // edges per bucket_scatter block

__device__ inline unsigned short f2bf(float f) {
    unsigned x = __float_as_uint(f);
    unsigned r = x + 0x7FFFu + ((x >> 16) & 1u);  // RNE
    return (unsigned short)(r >> 16);
}
__device__ inline float bf2f(unsigned short u) {
    return __uint_as_float(((unsigned)u) << 16);
}

// ---------- CSR build ----------

__global__ void bucket_hist_kernel(const int* __restrict__ ei, int* __restrict__ bcnt,
                                   int E, int NB) {
    __shared__ int lcnt[256];
    int t = threadIdx.x;
    lcnt[t] = 0;
    __syncthreads();
    int e0 = blockIdx.x * TILE;
    int n = min(TILE, E - e0);
    for (int r = 0; r < TILE / 256; ++r) {
        int i = r * 256 + t;
        if (i < n) atomicAdd(&lcnt[ei[E + e0 + i] >> BKT_SH], 1);
    }
    __syncthreads();
    if (t < NB && lcnt[t] > 0) atomicAdd(&bcnt[t], lcnt[t]);
}

__global__ void mini_scan_kernel(const int* __restrict__ bcnt, int* __restrict__ bbase,
                                 int* __restrict__ gcur, int NB) {
    __shared__ int a[256], c[256];
    int t = threadIdx.x;
    int v = (t < NB) ? bcnt[t] : 0;
    a[t] = v; c[t] = v;
    __syncthreads();
    for (int o = 1; o < 256; o <<= 1) {
        int w = (t >= o) ? a[t - o] : 0;
        __syncthreads();
        a[t] += w;
        __syncthreads();
    }
    int ex = a[t] - c[t];
    if (t < NB) { bbase[t] = ex; gcur[t] = ex; }
    if (t == 0) bbase[NB] = a[255];
}

__global__ void bucket_scatter_kernel(const int* __restrict__ ei, const float* __restrict__ ea,
                                      int* __restrict__ gcur, uint2* __restrict__ tpd,
                                      int E, int NB) {
    __shared__ unsigned spl[TILE];
    __shared__ unsigned short sdst[TILE];
    __shared__ unsigned short inv[TILE];
    __shared__ int lcnt[256], loff[256], lrank[256], gb[256];
    int t = threadIdx.x;
    lcnt[t] = 0; lrank[t] = 0;
    __syncthreads();
    int e0 = blockIdx.x * TILE;
    int n = min(TILE, E - e0);
    for (int r = 0; r < TILE / 256; ++r) {
        int i = r * 256 + t;
        if (i < n) {
            int e = e0 + i;
            int src = ei[e];
            int dst = ei[E + e];
            float u = ea[e];
            float v = u * (float)(KS - 1);
            float vf = floorf(v);
            int k0 = min(max((int)vf, 0), KS - 1);
            unsigned qf = (unsigned)((v - vf) * 16383.f + 0.5f);  // 14-bit frac
            spl[i] = ((unsigned)src << 2) | (unsigned)k0 | (qf << 18);  // srck | frac
            sdst[i] = (unsigned short)dst;
            atomicAdd(&lcnt[dst >> BKT_SH], 1);
        }
    }
    __syncthreads();
    loff[t] = lcnt[t];
    __syncthreads();
    for (int o = 1; o < 256; o <<= 1) {
        int w = (t >= o) ? loff[t - o] : 0;
        __syncthreads();
        loff[t] += w;
        __syncthreads();
    }
    int ex = loff[t] - lcnt[t];
    __syncthreads();
    loff[t] = ex;
    if (t < NB) gb[t] = atomicAdd(&gcur[t], lcnt[t]);
    __syncthreads();
    for (int r = 0; r < TILE / 256; ++r) {
        int i = r * 256 + t;
        if (i < n) {
            int b = sdst[i] >> BKT_SH;
            int p = loff[b] + atomicAdd(&lrank[b], 1);
            inv[p] = (unsigned short)i;
        }
    }
    __syncthreads();
    for (int r = 0; r < TILE / 256; ++r) {
        int j = r * 256 + t;
        if (j < n) {
            int i = inv[j];
            int d = sdst[i];
            int b = d >> BKT_SH;
            int pos = gb[b] + (j - loff[b]);
            tpd[pos] = make_uint2(spl[i], (unsigned)d);
        }
    }
}

// One block per bucket: sort by (dst_local, src_quartile) -> 1024 bins.
__global__ void node_sort_kernel(const uint2* __restrict__ tpd, const int* __restrict__ bbase,
                                 unsigned* __restrict__ spk, int* __restrict__ offs4,
                                 int N, int NB, int Q) {
    __shared__ int hc[1024], hs[1024], hr[1024], part[256];
    int b = blockIdx.x;
    int t = threadIdx.x;
    int nb0 = b << BKT_SH;
    int nb = min(256, N - nb0);
    int base = bbase[b];
    int m = bbase[b + 1] - base;
    for (int j = t; j < 1024; j += 256) { hc[j] = 0; hr[j] = 0; }
    __syncthreads();
    for (int i = t; i < m; i += 256) {
        uint2 r = tpd[base + i];
        int d = r.y - nb0;
        int src = (r.x >> 2) & 0xFFFF;
        int qt = (src >= Q) + (src >= 2 * Q) + (src >= 3 * Q);
        atomicAdd(&hc[(d << 2) | qt], 1);
    }
    __syncthreads();
    int s = hc[4 * t] + hc[4 * t + 1] + hc[4 * t + 2] + hc[4 * t + 3];
    part[t] = s;
    __syncthreads();
    for (int o = 1; o < 256; o <<= 1) {
        int w = (t >= o) ? part[t - o] : 0;
        __syncthreads();
        part[t] += w;
        __syncthreads();
    }
    int run = part[t] - s;
#pragma unroll
    for (int j = 0; j < 4; ++j) { hs[4 * t + j] = run; run += hc[4 * t + j]; }
    __syncthreads();
    for (int j = t; j < 4 * nb; j += 256) offs4[(nb0 << 2) + j] = base + hs[j];
    if (b == NB - 1 && t == 0) offs4[4 * N] = base + m;
    for (int i = t; i < m; i += 256) {
        uint2 r = tpd[base + i];
        int d = r.y - nb0;
        int src = (r.x >> 2) & 0xFFFF;
        int qt = (src >= Q) + (src >= 2 * Q) + (src >= 3 * Q);
        int bin = (d << 2) | qt;
        int p = hs[bin] + atomicAdd(&hr[bin], 1);
        spk[base + p] = r.x;
    }
}

// ---------- xw tables (LDS-staged W, register-blocked) ----------

__global__ __launch_bounds__(320) void xw1_kernel(
        const float* __restrict__ X, const float* __restrict__ W,
        const float* __restrict__ R, unsigned short* __restrict__ outk,
        float* __restrict__ outr, int n) {
    __shared__ float lw[48 * 160];
    int t = threadIdx.x;
    for (int i = t; i < 48 * 160; i += 320) {
        int f = i / 160;
        int col = i - f * 160;
        lw[i] = (col < 128) ? W[(size_t)(col >> 5) * (48 * 32) + f * 32 + (col & 31)]
                            : R[f * 32 + (col - 128)];
    }
    __syncthreads();
    int g = t % 40;      // colgroup (4 cols)
    int lp = t / 40;     // local pair 0..7
    int n0 = (blockIdx.x * 8 + lp) * 2;
    if (n0 + 1 >= n) return;
    const float4* X0 = (const float4*)(X + (size_t)n0 * F_IN);
    const float4* X1 = (const float4*)(X + (size_t)(n0 + 1) * F_IN);
    float4 x0[12], x1[12];
#pragma unroll
    for (int i = 0; i < 12; ++i) { x0[i] = X0[i]; x1[i] = X1[i]; }
    const float4* lw4 = (const float4*)lw;  // lw4[f*40 + g]
    float4 a0 = {0,0,0,0}, a1 = {0,0,0,0};
#pragma unroll
    for (int fb = 0; fb < 12; ++fb) {
        float4 v0 = x0[fb], v1 = x1[fb];
#pragma unroll
        for (int j = 0; j < 4; ++j) {
            float s0 = (j == 0) ? v0.x : (j == 1) ? v0.y : (j == 2) ? v0.z : v0.w;
            float s1 = (j == 0) ? v1.x : (j == 1) ? v1.y : (j == 2) ? v1.z : v1.w;
            float4 w = lw4[(fb * 4 + j) * 40 + g];
            a0.x = fmaf(s0, w.x, a0.x); a0.y = fmaf(s0, w.y, a0.y);
            a0.z = fmaf(s0, w.z, a0.z); a0.w = fmaf(s0, w.w, a0.w);
            a1.x = fmaf(s1, w.x, a1.x); a1.y = fmaf(s1, w.y, a1.y);
            a1.z = fmaf(s1, w.z, a1.z); a1.w = fmaf(s1, w.w, a1.w);
        }
    }
    if (g < 32) {
        uint2 u0, u1;
        u0.x = f2bf(a0.x) | ((unsigned)f2bf(a0.y) << 16);
        u0.y = f2bf(a0.z) | ((unsigned)f2bf(a0.w) << 16);
        u1.x = f2bf(a1.x) | ((unsigned)f2bf(a1.y) << 16);
        u1.y = f2bf(a1.z) | ((unsigned)f2bf(a1.w) << 16);
        *(uint2*)(outk + (size_t)n0 * (KS * HID) + g * 4) = u0;
        *(uint2*)(outk + (size_t)(n0 + 1) * (KS * HID) + g * 4) = u1;
    } else {
        int o = 4 * g - 128;
        *(float4*)(outr + (size_t)n0 * HID + o) = a0;
        *(float4*)(outr + (size_t)(n0 + 1) * HID + o) = a1;
    }
}

__global__ void xw2_kernel(const float* __restrict__ H, const float* __restrict__ W,
                           const float* __restrict__ R, unsigned short* __restrict__ outk,
                           float* __restrict__ outr, int n) {
    __shared__ float lw2[32 * 50];
    int t = threadIdx.x;
    for (int i = t; i < 32 * 50; i += 256) {
        int f = i / 50;
        int col = i - f * 50;
        lw2[i] = (col < 40) ? W[(size_t)(col / 10) * (32 * 10) + f * 10 + (col % 10)]
                            : R[f * 10 + (col - 40)];
    }
    __syncthreads();
    int total = (n / 2) * 25;
    int id = blockIdx.x * blockDim.x + t;
    if (id >= total) return;
    int p = id % 25;
    int pr = id / 25;
    int n0 = 2 * pr;
    const float4* H0 = (const float4*)(H + (size_t)n0 * HID);
    const float4* H1 = (const float4*)(H + (size_t)(n0 + 1) * HID);
    float4 h0[8], h1[8];
#pragma unroll
    for (int i = 0; i < 8; ++i) { h0[i] = H0[i]; h1[i] = H1[i]; }
    const float2* lwp = (const float2*)lw2;  // lwp[f*25 + p]
    float ax0 = 0.f, ay0 = 0.f, ax1 = 0.f, ay1 = 0.f;
#pragma unroll
    for (int fb = 0; fb < 8; ++fb) {
        float4 v0 = h0[fb], v1 = h1[fb];
#pragma unroll
        for (int j = 0; j < 4; ++j) {
            float s0 = (j == 0) ? v0.x : (j == 1) ? v0.y : (j == 2) ? v0.z : v0.w;
            float s1 = (j == 0) ? v1.x : (j == 1) ? v1.y : (j == 2) ? v1.z : v1.w;
            float2 w = lwp[(fb * 4 + j) * 25 + p];
            ax0 = fmaf(s0, w.x, ax0); ay0 = fmaf(s0, w.y, ay0);
            ax1 = fmaf(s1, w.x, ax1); ay1 = fmaf(s1, w.y, ay1);
        }
    }
    int col = 2 * p;
    if (col < 40) {           // col = k*10+o; 10 even -> pair never straddles k
        int k = col / 10;
        int o = col - k * 10;
        *(unsigned*)(outk + (size_t)n0 * 64 + k * 16 + o) =
            f2bf(ax0) | ((unsigned)f2bf(ay0) << 16);
        *(unsigned*)(outk + (size_t)(n0 + 1) * 64 + k * 16 + o) =
            f2bf(ax1) | ((unsigned)f2bf(ay1) << 16);
    } else {
        int o = col - 40;
        *(float2*)(outr + (size_t)n0 * NCLS + o) = make_float2(ax0, ay0);
        *(float2*)(outr + (size_t)(n0 + 1) * NCLS + o) = make_float2(ax1, ay1);
    }
}

// ---------- aggregation (src-quartile sharded, store-based partials) ----------

__device__ inline float g32(const unsigned short* __restrict__ tbl, unsigned p) {
    unsigned sk = p & 0x3FFFFu;           // src*4 + k0 ; row = 32 ushorts
    float fr = (float)(p >> 18) * (1.f / 16383.f);
    float v0 = bf2f(tbl[sk * 32]);
    float v1 = bf2f(tbl[sk * 32 + 32]);   // k0+1 row (k0<=2 always)
    return fmaf(fr, v1 - v0, v0);
}

// Block = 4 waves = 4 nodes, one quartile (blockIdx&3 -> XCD-pinned).
// Wave: 2 edge-slots x 32 ch, 2x unroll (4 edges in flight). Partial sum
// stored unconditionally (no atomics, no memset).
__global__ void agg1_kernel(const unsigned short* __restrict__ xwk,
                            const int* __restrict__ offs4, const unsigned* __restrict__ spk,
                            float* __restrict__ hacc4, int n) {
    int lane = threadIdx.x & 63;
    int c = lane & 31;
    int slot = lane >> 5;
    int qt = blockIdx.x & 3;
    int node = (blockIdx.x >> 2) * 4 + (threadIdx.x >> 6);
    if (node >= n) return;
    int beg = offs4[node * 4 + qt], end = offs4[node * 4 + qt + 1];
    const unsigned short* tbl = xwk + c;
    float s0 = 0.f, s1 = 0.f;
    int e = beg + slot;
    for (; e + 2 < end; e += 4) {
        unsigned p0 = __builtin_nontemporal_load(spk + e);
        unsigned p1 = __builtin_nontemporal_load(spk + e + 2);
        s0 += g32(tbl, p0);
        s1 += g32(tbl, p1);
    }
    if (e < end) s0 += g32(tbl, __builtin_nontemporal_load(spk + e));
    float sum = s0 + s1;
    sum += __shfl_xor(sum, 32, 64);
    if (slot == 0) hacc4[((size_t)qt * n + node) * HID + c] = sum;
}

__global__ void fin1_kernel(const float* __restrict__ hacc4, const float* __restrict__ xr,
                            const int* __restrict__ offs4, const float* __restrict__ bias,
                            float* __restrict__ h, int n) {
    int id = blockIdx.x * 256 + threadIdx.x;
    if (id >= n * HID) return;
    int node = id >> 5, c = id & 31;
    int deg = offs4[node * 4 + 4] - offs4[node * 4];
    size_t qs = (size_t)n * HID;
    float sum = hacc4[id] + hacc4[qs + id] + hacc4[2 * qs + id] + hacc4[3 * qs + id];
    float m = sum / (float)(deg > 0 ? deg : 1);
    float o = m + xr[id] + bias[c];
    h[id] = (o > 0.f) ? o : expm1f(o);
}

__device__ inline float g16(const unsigned short* __restrict__ tbl, unsigned p) {
    unsigned sk = p & 0x3FFFFu;           // row = 16 ushorts
    float fr = (float)(p >> 18) * (1.f / 16383.f);
    float v0 = bf2f(tbl[sk * 16]);
    float v1 = bf2f(tbl[sk * 16 + 16]);
    return fmaf(fr, v1 - v0, v0);
}

// Wave: 4 edge-slots x 16 ch, 2x unroll (8 edges in flight).
__global__ void agg2_kernel(const unsigned short* __restrict__ xwk,
                            const int* __restrict__ offs4, const unsigned* __restrict__ spk,
                            float* __restrict__ lacc4, int n) {
    int lane = threadIdx.x & 63;
    int c = lane & 15;
    int slot = lane >> 4;
    int qt = blockIdx.x & 3;
    int node = (blockIdx.x >> 2) * 4 + (threadIdx.x >> 6);
    if (node >= n) return;
    int beg = offs4[node * 4 + qt], end = offs4[node * 4 + qt + 1];
    const unsigned short* tbl = xwk + c;
    float s0 = 0.f, s1 = 0.f;
    int e = beg + slot;
    for (; e + 4 < end; e += 8) {
        unsigned p0 = __builtin_nontemporal_load(spk + e);
        unsigned p1 = __builtin_nontemporal_load(spk + e + 4);
        s0 += g16(tbl, p0);
        s1 += g16(tbl, p1);
    }
    if (e < end) s0 += g16(tbl, __builtin_nontemporal_load(spk + e));
    float sum = s0 + s1;
    sum += __shfl_xor(sum, 16, 64);
    sum += __shfl_xor(sum, 32, 64);
    if (lane < 16) lacc4[((size_t)qt * n + node) * 16 + c] = sum;
}

__global__ void fin2_kernel(const float* __restrict__ lacc4, const float* __restrict__ xr,
                            const int* __restrict__ offs4, const float* __restrict__ bias,
                            float* __restrict__ out, int n) {
    int i = blockIdx.x * 256 + threadIdx.x;
    if (i >= n) return;
    int deg = offs4[i * 4 + 4] - offs4[i * 4];
    float inv = 1.f / (float)(deg > 0 ? deg : 1);
    size_t qs = (size_t)n * 16;
    float v[10];
    const float* rr = xr + (size_t)i * NCLS;
#pragma unroll
    for (int j = 0; j < 10; ++j) {
        size_t idx = (size_t)i * 16 + j;
        float s = lacc4[idx] + lacc4[qs + idx] + lacc4[2 * qs + idx] + lacc4[3 * qs + idx];
        v[j] = s * inv + rr[j] + bias[j];
    }
    float mx = v[0];
#pragma unroll
    for (int j = 1; j < 10; ++j) mx = fmaxf(mx, v[j]);
    float s = 0.f;
#pragma unroll
    for (int j = 0; j < 10; ++j) s += expf(v[j] - mx);
    float ls = logf(s) + mx;
    float* o = out + (size_t)i * 10;
#pragma unroll
    for (int j = 0; j < 10; ++j) o[j] = v[j] - ls;
}

extern "C" void kernel_launch(void* const* d_in, const int* in_sizes, int n_in,
                              void* d_out, int out_size, void* d_ws, size_t ws_size,
                              hipStream_t stream) {
    const float* x       = (const float*)d_in[0];
    const int*   ei      = (const int*)d_in[1];
    const float* ea      = (const float*)d_in[2];
    const float* W1      = (const float*)d_in[3];
    const float* root1   = (const float*)d_in[4];
    const float* bias1   = (const float*)d_in[5];
    const float* W2      = (const float*)d_in[6];
    const float* root2   = (const float*)d_in[7];
    const float* bias2   = (const float*)d_in[8];
    float* out = (float*)d_out;

    const int N = in_sizes[0] / F_IN;      // 50000
    const int E = in_sizes[2];             // 1600000
    const int NB = (N + 255) >> BKT_SH;    // 196
    const int Q  = (N + 3) / 4;            // src-quartile width (12500)

    char* base = (char*)d_ws;
    size_t off = 0;
    auto alloc = [&](size_t bytes) {
        char* p = base + off;
        off = (off + bytes + 255) & ~(size_t)255;
        return (void*)p;
    };
    unsigned short* xwk1 = (unsigned short*)alloc((size_t)N * 128 * 2);   // 12.8 MB
    float* xr1           = (float*)alloc((size_t)N * HID * 4);            // 6.4 MB
    float* h             = (float*)alloc((size_t)N * HID * 4);            // 6.4 MB
    float* hacc4         = (float*)alloc((size_t)4 * N * HID * 4);        // 25.6 MB
    int* offs4           = (int*)alloc(((size_t)4 * N + 1) * 4);          // 0.8 MB
    int* bcnt            = (int*)alloc((size_t)NB * 4);
    int* bbase           = (int*)alloc(((size_t)NB + 1) * 4);
    int* gcur            = (int*)alloc((size_t)NB * 4);
    unsigned* spk        = (unsigned*)alloc((size_t)E * 4);               // 6.4 MB
    uint2* tpd           = (uint2*)xwk1;   // E*8 = 12.8MB (dead before xw1)
    unsigned short* xwk2 = xwk1;           // N*64 ushorts, aliases layer-1
    // lacc4 (4*N*16 fp32 = 12.8MB) and xr2 (2MB) alias hacc4 (dead after fin1)
    float* lacc4         = hacc4;
    float* xr2           = hacc4 + (size_t)4 * N * 16;
    if (ws_size < off) return;

    int ebk = (E + TILE - 1) / TILE;

    hipMemsetAsync(bcnt, 0, (size_t)NB * 4, stream);
    bucket_hist_kernel<<<ebk, 256, 0, stream>>>(ei, bcnt, E, NB);
    mini_scan_kernel<<<1, 256, 0, stream>>>(bcnt, bbase, gcur, NB);
    bucket_scatter_kernel<<<ebk, 256, 0, stream>>>(ei, ea, gcur, tpd, E, NB);
    node_sort_kernel<<<NB, 256, 0, stream>>>(tpd, bbase, spk, offs4, N, NB, Q);
    // xw1 after node_sort (tpd aliases xwk1)
    xw1_kernel<<<(N + 15) / 16, 320, 0, stream>>>(x, W1, root1, xwk1, xr1, N);
    agg1_kernel<<<((N + 3) / 4) * 4, 256, 0, stream>>>(xwk1, offs4, spk, hacc4, N);
    fin1_kernel<<<(N * HID + 255) / 256, 256, 0, stream>>>(hacc4, xr1, offs4, bias1, h, N);
    {
        int total = (N / 2) * 25;
        xw2_kernel<<<(total + 255) / 256, 256, 0, stream>>>(h, W2, root2, xwk2, xr2, N);
    }
    agg2_kernel<<<((N + 3) / 4) * 4, 256, 0, stream>>>(xwk2, offs4, spk, lacc4, N);
    fin2_kernel<<<(N + 255) / 256, 256, 0, stream>>>(lacc4, xr2, offs4, bias2, out, N);
}

// Round 10
// 289.884 us; speedup vs baseline: 1.2039x; 1.1952x over previous
//
#include <hip/hip_runtime.h>
#include <math.h>

// SplineConv x2 (K=4, dim=1, degree=1, mean aggr) + ELU + log_softmax.
// R10: sharding (R7-R9) regressed despite FETCH 104->33MB -- the gather is
// random-TRANSACTION bound, not byte-bound, and sharding quartered loop
// length while 4x-ing waves. Revert to R6 agg structure (wave per node,
// long loops); halve transactions instead with PAIR-INTERLEAVED tables:
// per (src, p in {0,1,2}): uint[c] = bf16(row_p[c]) | bf16(row_{p+1}[c])<<16.
// One edge = ONE wave load: 128B contiguous (layer1), 64B = 1 line (layer2).
// Payload = (src*3+k0) | qf<<18; k0 clamped to 2 with fr=v-k0 (xw[3] ==
// pair2 @ fr=1). Proven xw kernels unchanged; tiny pairify kernels convert.

#define F_IN   48
#define HID    32
#define NCLS   10
#define KS     4
#define BKT_SH 8               // 256 nodes per bucket
#define TILE   4096            // edges per bucket_scatter block

__device__ inline unsigned short f2bf(float f) {
    unsigned x = __float_as_uint(f);
    unsigned r = x + 0x7FFFu + ((x >> 16) & 1u);  // RNE
    return (unsigned short)(r >> 16);
}
__device__ inline float bf2f(unsigned short u) {
    return __uint_as_float(((unsigned)u) << 16);
}

// ---------- CSR build ----------

__global__ void bucket_hist_kernel(const int* __restrict__ ei, int* __restrict__ bcnt,
                                   int E, int NB) {
    __shared__ int lcnt[256];
    int t = threadIdx.x;
    lcnt[t] = 0;
    __syncthreads();
    int e0 = blockIdx.x * TILE;
    int n = min(TILE, E - e0);
    for (int r = 0; r < TILE / 256; ++r) {
        int i = r * 256 + t;
        if (i < n) atomicAdd(&lcnt[ei[E + e0 + i] >> BKT_SH], 1);
    }
    __syncthreads();
    if (t < NB && lcnt[t] > 0) atomicAdd(&bcnt[t], lcnt[t]);
}

__global__ void mini_scan_kernel(const int* __restrict__ bcnt, int* __restrict__ bbase,
                                 int* __restrict__ gcur, int NB) {
    __shared__ int a[256], c[256];
    int t = threadIdx.x;
    int v = (t < NB) ? bcnt[t] : 0;
    a[t] = v; c[t] = v;
    __syncthreads();
    for (int o = 1; o < 256; o <<= 1) {
        int w = (t >= o) ? a[t - o] : 0;
        __syncthreads();
        a[t] += w;
        __syncthreads();
    }
    int ex = a[t] - c[t];
    if (t < NB) { bbase[t] = ex; gcur[t] = ex; }
    if (t == 0) bbase[NB] = a[255];
}

__global__ void bucket_scatter_kernel(const int* __restrict__ ei, const float* __restrict__ ea,
                                      int* __restrict__ gcur, uint2* __restrict__ tpd,
                                      int E, int NB) {
    __shared__ unsigned spl[TILE];
    __shared__ unsigned short sdst[TILE];
    __shared__ unsigned short inv[TILE];
    __shared__ int lcnt[256], loff[256], lrank[256], gb[256];
    int t = threadIdx.x;
    lcnt[t] = 0; lrank[t] = 0;
    __syncthreads();
    int e0 = blockIdx.x * TILE;
    int n = min(TILE, E - e0);
    for (int r = 0; r < TILE / 256; ++r) {
        int i = r * 256 + t;
        if (i < n) {
            int e = e0 + i;
            int src = ei[e];
            int dst = ei[E + e];
            float u = ea[e];
            float v = u * (float)(KS - 1);
            float vf = floorf(v);
            int k0 = min(max((int)vf, 0), 2);          // clamp to 2 (pair id)
            float fr = v - (float)k0;                  // fr=1 when v hits 3.0
            unsigned qf = (unsigned)(fr * 16383.f + 0.5f);  // 14-bit frac
            spl[i] = (unsigned)(src * 3 + k0) | (qf << 18);
            sdst[i] = (unsigned short)dst;
            atomicAdd(&lcnt[dst >> BKT_SH], 1);
        }
    }
    __syncthreads();
    loff[t] = lcnt[t];
    __syncthreads();
    for (int o = 1; o < 256; o <<= 1) {
        int w = (t >= o) ? loff[t - o] : 0;
        __syncthreads();
        loff[t] += w;
        __syncthreads();
    }
    int ex = loff[t] - lcnt[t];
    __syncthreads();
    loff[t] = ex;
    if (t < NB) gb[t] = atomicAdd(&gcur[t], lcnt[t]);
    __syncthreads();
    for (int r = 0; r < TILE / 256; ++r) {
        int i = r * 256 + t;
        if (i < n) {
            int b = sdst[i] >> BKT_SH;
            int p = loff[b] + atomicAdd(&lrank[b], 1);
            inv[p] = (unsigned short)i;
        }
    }
    __syncthreads();
    for (int r = 0; r < TILE / 256; ++r) {
        int j = r * 256 + t;
        if (j < n) {
            int i = inv[j];
            int d = sdst[i];
            int b = d >> BKT_SH;
            int pos = gb[b] + (j - loff[b]);
            tpd[pos] = make_uint2(spl[i], (unsigned)d);
        }
    }
}

// One block per bucket: sort bucket's edges by node, emit spk + offs[N+1].
__global__ void node_sort_kernel(const uint2* __restrict__ tpd, const int* __restrict__ bbase,
                                 unsigned* __restrict__ spk, int* __restrict__ offs,
                                 int N, int NB) {
    __shared__ int hc[256], hs[256], hr[256];
    int b = blockIdx.x;
    int t = threadIdx.x;
    int nb0 = b << BKT_SH;
    int nb = min(256, N - nb0);
    int base = bbase[b];
    int m = bbase[b + 1] - base;
    hc[t] = 0; hr[t] = 0;
    __syncthreads();
    for (int i = t; i < m; i += 256) atomicAdd(&hc[tpd[base + i].y - nb0], 1);
    __syncthreads();
    hs[t] = hc[t];
    __syncthreads();
    for (int o = 1; o < 256; o <<= 1) {
        int w = (t >= o) ? hs[t - o] : 0;
        __syncthreads();
        hs[t] += w;
        __syncthreads();
    }
    if (t < nb) offs[nb0 + t] = base + (hs[t] - hc[t]);
    if (b == NB - 1 && t == 0) offs[N] = base + m;
    for (int i = t; i < m; i += 256) {
        uint2 rec = tpd[base + i];
        int d = rec.y - nb0;
        int p = (hs[d] - hc[d]) + atomicAdd(&hr[d], 1);
        spk[base + p] = rec.x;
    }
}

// ---------- xw tables (LDS-staged W; plain layouts, unchanged) ----------

__global__ __launch_bounds__(320) void xw1_kernel(
        const float* __restrict__ X, const float* __restrict__ W,
        const float* __restrict__ R, unsigned short* __restrict__ outk,
        float* __restrict__ outr, int n) {
    __shared__ float lw[48 * 160];
    int t = threadIdx.x;
    for (int i = t; i < 48 * 160; i += 320) {
        int f = i / 160;
        int col = i - f * 160;
        lw[i] = (col < 128) ? W[(size_t)(col >> 5) * (48 * 32) + f * 32 + (col & 31)]
                            : R[f * 32 + (col - 128)];
    }
    __syncthreads();
    int g = t % 40;      // colgroup (4 cols)
    int lp = t / 40;     // local pair 0..7
    int n0 = (blockIdx.x * 8 + lp) * 2;
    if (n0 + 1 >= n) return;
    const float4* X0 = (const float4*)(X + (size_t)n0 * F_IN);
    const float4* X1 = (const float4*)(X + (size_t)(n0 + 1) * F_IN);
    float4 x0[12], x1[12];
#pragma unroll
    for (int i = 0; i < 12; ++i) { x0[i] = X0[i]; x1[i] = X1[i]; }
    const float4* lw4 = (const float4*)lw;  // lw4[f*40 + g]
    float4 a0 = {0,0,0,0}, a1 = {0,0,0,0};
#pragma unroll
    for (int fb = 0; fb < 12; ++fb) {
        float4 v0 = x0[fb], v1 = x1[fb];
#pragma unroll
        for (int j = 0; j < 4; ++j) {
            float s0 = (j == 0) ? v0.x : (j == 1) ? v0.y : (j == 2) ? v0.z : v0.w;
            float s1 = (j == 0) ? v1.x : (j == 1) ? v1.y : (j == 2) ? v1.z : v1.w;
            float4 w = lw4[(fb * 4 + j) * 40 + g];
            a0.x = fmaf(s0, w.x, a0.x); a0.y = fmaf(s0, w.y, a0.y);
            a0.z = fmaf(s0, w.z, a0.z); a0.w = fmaf(s0, w.w, a0.w);
            a1.x = fmaf(s1, w.x, a1.x); a1.y = fmaf(s1, w.y, a1.y);
            a1.z = fmaf(s1, w.z, a1.z); a1.w = fmaf(s1, w.w, a1.w);
        }
    }
    if (g < 32) {  // plain [node][k][32c] bf16
        uint2 u0, u1;
        u0.x = f2bf(a0.x) | ((unsigned)f2bf(a0.y) << 16);
        u0.y = f2bf(a0.z) | ((unsigned)f2bf(a0.w) << 16);
        u1.x = f2bf(a1.x) | ((unsigned)f2bf(a1.y) << 16);
        u1.y = f2bf(a1.z) | ((unsigned)f2bf(a1.w) << 16);
        *(uint2*)(outk + (size_t)n0 * (KS * HID) + g * 4) = u0;
        *(uint2*)(outk + (size_t)(n0 + 1) * (KS * HID) + g * 4) = u1;
    } else {
        int o = 4 * g - 128;
        *(float4*)(outr + (size_t)n0 * HID + o) = a0;
        *(float4*)(outr + (size_t)(n0 + 1) * HID + o) = a1;
    }
}

__global__ void xw2_kernel(const float* __restrict__ H, const float* __restrict__ W,
                           const float* __restrict__ R, unsigned short* __restrict__ outk,
                           float* __restrict__ outr, int n) {
    __shared__ float lw2[32 * 50];
    int t = threadIdx.x;
    for (int i = t; i < 32 * 50; i += 256) {
        int f = i / 50;
        int col = i - f * 50;
        lw2[i] = (col < 40) ? W[(size_t)(col / 10) * (32 * 10) + f * 10 + (col % 10)]
                            : R[f * 10 + (col - 40)];
    }
    __syncthreads();
    int total = (n / 2) * 25;
    int id = blockIdx.x * blockDim.x + t;
    if (id >= total) return;
    int p = id % 25;
    int pr = id / 25;
    int n0 = 2 * pr;
    const float4* H0 = (const float4*)(H + (size_t)n0 * HID);
    const float4* H1 = (const float4*)(H + (size_t)(n0 + 1) * HID);
    float4 h0[8], h1[8];
#pragma unroll
    for (int i = 0; i < 8; ++i) { h0[i] = H0[i]; h1[i] = H1[i]; }
    const float2* lwp = (const float2*)lw2;  // lwp[f*25 + p]
    float ax0 = 0.f, ay0 = 0.f, ax1 = 0.f, ay1 = 0.f;
#pragma unroll
    for (int fb = 0; fb < 8; ++fb) {
        float4 v0 = h0[fb], v1 = h1[fb];
#pragma unroll
        for (int j = 0; j < 4; ++j) {
            float s0 = (j == 0) ? v0.x : (j == 1) ? v0.y : (j == 2) ? v0.z : v0.w;
            float s1 = (j == 0) ? v1.x : (j == 1) ? v1.y : (j == 2) ? v1.z : v1.w;
            float2 w = lwp[(fb * 4 + j) * 25 + p];
            ax0 = fmaf(s0, w.x, ax0); ay0 = fmaf(s0, w.y, ay0);
            ax1 = fmaf(s1, w.x, ax1); ay1 = fmaf(s1, w.y, ay1);
        }
    }
    int col = 2 * p;
    if (col < 40) {           // plain [node][k][16c] bf16 (10..15 unused)
        int k = col / 10;
        int o = col - k * 10;
        *(unsigned*)(outk + (size_t)n0 * 64 + k * 16 + o) =
            f2bf(ax0) | ((unsigned)f2bf(ay0) << 16);
        *(unsigned*)(outk + (size_t)(n0 + 1) * 64 + k * 16 + o) =
            f2bf(ax1) | ((unsigned)f2bf(ay1) << 16);
    } else {
        int o = col - 40;
        *(float2*)(outr + (size_t)n0 * NCLS + o) = make_float2(ax0, ay0);
        *(float2*)(outr + (size_t)(n0 + 1) * NCLS + o) = make_float2(ax1, ay1);
    }
}

// ---------- pairify: plain -> pair-interleaved uint tables ----------

// Layer1: out[node*96 + p*32 + c] = in[node*128+p*32+c] | in[..+32+c]<<16
__global__ void pairify1_kernel(const unsigned short* __restrict__ in,
                                unsigned* __restrict__ out, int total) {
    int id = blockIdx.x * 256 + threadIdx.x;
    if (id >= total) return;
    int c = id & 31;
    int rest = id >> 5;        // node*3 + p
    int node = rest / 3;
    int ib = (rest + node) * 32 + c;   // node*128 + p*32 + c
    out[id] = (unsigned)in[ib] | ((unsigned)in[ib + 32] << 16);
}

// Layer2: out[node*48 + p*16 + c] = in[node*64+p*16+c] | in[..+16+c]<<16
__global__ void pairify2_kernel(const unsigned short* __restrict__ in,
                                unsigned* __restrict__ out, int total) {
    int id = blockIdx.x * 256 + threadIdx.x;
    if (id >= total) return;
    int c = id & 15;
    int rest = id >> 4;        // node*3 + p
    int node = rest / 3;
    int ib = (rest + node) * 16 + c;   // node*64 + p*16 + c
    out[id] = (unsigned)in[ib] | ((unsigned)in[ib + 16] << 16);
}

// ---------- aggregation (wave per node, paired gathers) ----------

__device__ inline float ginterp(const unsigned* __restrict__ t, unsigned p, int rowlen) {
    unsigned w = t[(p & 0x3FFFFu) * rowlen];
    float v0 = bf2f((unsigned short)w);
    float v1 = bf2f((unsigned short)(w >> 16));
    return fmaf((float)(p >> 18) * (1.f / 16383.f), v1 - v0, v0);
}

// Wave = node; lanes = 2 halves x 32 ch; 4-deep unroll = 8 loads in flight.
__global__ void agg1_kernel(const unsigned* __restrict__ tbl, const float* __restrict__ xr,
                            const int* __restrict__ offs, const unsigned* __restrict__ spk,
                            const float* __restrict__ bias, float* __restrict__ h, int n) {
    int lane = threadIdx.x & 63;
    int c = lane & 31;
    int half = lane >> 5;
    int node = blockIdx.x * 4 + (threadIdx.x >> 6);
    if (node >= n) return;
    int beg = offs[node], end = offs[node + 1];
    const unsigned* t = tbl + c;
    float s0 = 0.f, s1 = 0.f, s2 = 0.f, s3 = 0.f;
    int e = beg + half;
    for (; e + 6 < end; e += 8) {
        unsigned p0 = __builtin_nontemporal_load(spk + e);
        unsigned p1 = __builtin_nontemporal_load(spk + e + 2);
        unsigned p2 = __builtin_nontemporal_load(spk + e + 4);
        unsigned p3 = __builtin_nontemporal_load(spk + e + 6);
        s0 += ginterp(t, p0, 32);
        s1 += ginterp(t, p1, 32);
        s2 += ginterp(t, p2, 32);
        s3 += ginterp(t, p3, 32);
    }
    for (; e < end; e += 2)
        s0 += ginterp(t, __builtin_nontemporal_load(spk + e), 32);
    float sum = (s0 + s1) + (s2 + s3);
    sum += __shfl_xor(sum, 32, 64);  // merge halves
    if (half == 0) {
        int deg = end - beg;
        float m = sum / (float)(deg > 0 ? deg : 1);
        float o = m + xr[(size_t)node * HID + c] + bias[c];
        h[(size_t)node * HID + c] = (o > 0.f) ? o : expm1f(o);
    }
}

// Wave = node; lanes = 4 slots x 16 ch; 2x unroll = 8 loads in flight.
// One 64B line per edge. In-wave log_softmax epilogue.
__global__ void agg2_kernel(const unsigned* __restrict__ tbl, const float* __restrict__ xr,
                            const int* __restrict__ offs, const unsigned* __restrict__ spk,
                            const float* __restrict__ bias, float* __restrict__ out, int n) {
    int lane = threadIdx.x & 63;
    int c = lane & 15;
    int slot = lane >> 4;
    int node = blockIdx.x * 4 + (threadIdx.x >> 6);
    if (node >= n) return;
    int beg = offs[node], end = offs[node + 1];
    const unsigned* t = tbl + c;
    float s0 = 0.f, s1 = 0.f;
    int e = beg + slot;
    for (; e + 4 < end; e += 8) {
        unsigned p0 = __builtin_nontemporal_load(spk + e);
        unsigned p1 = __builtin_nontemporal_load(spk + e + 4);
        s0 += ginterp(t, p0, 16);
        s1 += ginterp(t, p1, 16);
    }
    if (e < end) s0 += ginterp(t, __builtin_nontemporal_load(spk + e), 16);
    float sum = s0 + s1;
    sum += __shfl_xor(sum, 16, 64);
    sum += __shfl_xor(sum, 32, 64);  // all lanes: channel-c total
    int deg = end - beg;
    float m = sum / (float)(deg > 0 ? deg : 1);
    int cc = min(c, NCLS - 1);
    float logit = m + xr[(size_t)node * NCLS + cc] + bias[cc];
    bool active = (c < NCLS);
    float mx = active ? logit : -INFINITY;
#pragma unroll
    for (int msk = 1; msk < 16; msk <<= 1) mx = fmaxf(mx, __shfl_xor(mx, msk, 16));
    float ex = active ? expf(logit - mx) : 0.f;
    float s = ex;
#pragma unroll
    for (int msk = 1; msk < 16; msk <<= 1) s += __shfl_xor(s, msk, 16);
    if (active && slot == 0) out[(size_t)node * NCLS + c] = (logit - mx) - logf(s);
}

extern "C" void kernel_launch(void* const* d_in, const int* in_sizes, int n_in,
                              void* d_out, int out_size, void* d_ws, size_t ws_size,
                              hipStream_t stream) {
    const float* x       = (const float*)d_in[0];
    const int*   ei      = (const int*)d_in[1];
    const float* ea      = (const float*)d_in[2];
    const float* W1      = (const float*)d_in[3];
    const float* root1   = (const float*)d_in[4];
    const float* bias1   = (const float*)d_in[5];
    const float* W2      = (const float*)d_in[6];
    const float* root2   = (const float*)d_in[7];
    const float* bias2   = (const float*)d_in[8];
    float* out = (float*)d_out;

    const int N = in_sizes[0] / F_IN;      // 50000
    const int E = in_sizes[2];             // 1600000
    const int NB = (N + 255) >> BKT_SH;    // 196

    char* base = (char*)d_ws;
    size_t off = 0;
    auto alloc = [&](size_t bytes) {
        char* p = base + off;
        off = (off + bytes + 255) & ~(size_t)255;
        return (void*)p;
    };
    unsigned short* xwk1p = (unsigned short*)alloc((size_t)N * 128 * 2);  // 12.8 MB plain
    unsigned* xwk1        = (unsigned*)alloc((size_t)N * 96 * 4);         // 19.2 MB paired
    float* xr1            = (float*)alloc((size_t)N * HID * 4);           // 6.4 MB
    float* h              = (float*)alloc((size_t)N * HID * 4);           // 6.4 MB
    float* xr2            = (float*)alloc((size_t)N * NCLS * 4);          // 2.0 MB
    int* offs             = (int*)alloc(((size_t)N + 1) * 4);
    int* bcnt             = (int*)alloc((size_t)NB * 4);
    int* bbase            = (int*)alloc(((size_t)NB + 1) * 4);
    int* gcur             = (int*)alloc((size_t)NB * 4);
    unsigned* spk         = (unsigned*)alloc((size_t)E * 4);              // 6.4 MB
    uint2* tpd            = (uint2*)xwk1p;   // 12.8 MB alias (dead before xw1)
    unsigned short* xwk2p = xwk1p;           // N*64 ush alias (xwk1p dead after pairify1)
    unsigned* xwk2        = xwk1;            // N*48 uint alias (xwk1 dead after agg1)
    if (ws_size < off) return;

    int ebk = (E + TILE - 1) / TILE;

    hipMemsetAsync(bcnt, 0, (size_t)NB * 4, stream);
    bucket_hist_kernel<<<ebk, 256, 0, stream>>>(ei, bcnt, E, NB);
    mini_scan_kernel<<<1, 256, 0, stream>>>(bcnt, bbase, gcur, NB);
    bucket_scatter_kernel<<<ebk, 256, 0, stream>>>(ei, ea, gcur, tpd, E, NB);
    node_sort_kernel<<<NB, 256, 0, stream>>>(tpd, bbase, spk, offs, N, NB);
    // xw1 after node_sort (tpd aliases xwk1p)
    xw1_kernel<<<(N + 15) / 16, 320, 0, stream>>>(x, W1, root1, xwk1p, xr1, N);
    pairify1_kernel<<<(N * 96 + 255) / 256, 256, 0, stream>>>(xwk1p, xwk1, N * 96);
    agg1_kernel<<<(N + 3) / 4, 256, 0, stream>>>(xwk1, xr1, offs, spk, bias1, h, N);
    {
        int total = (N / 2) * 25;
        xw2_kernel<<<(total + 255) / 256, 256, 0, stream>>>(h, W2, root2, xwk2p, xr2, N);
    }
    pairify2_kernel<<<(N * 48 + 255) / 256, 256, 0, stream>>>(xwk2p, xwk2, N * 48);
    agg2_kernel<<<(N + 3) / 4, 256, 0, stream>>>(xwk2, xr2, offs, spk, bias2, out, N);
}

// Round 11
// 283.833 us; speedup vs baseline: 1.2296x; 1.0213x over previous
//
#include <hip/hip_runtime.h>
#include <hip/hip_fp8.h>
#include <math.h>

// SplineConv x2 (K=4, dim=1, degree=1, mean aggr) + ELU + log_softmax.
// R11: agg gathers sit at the ~2TB/s random-line ceiling (R5-R10); only
// lever left is bytes/edge. Tables now fp8 e4m3 pair-interleaved:
// ushort[c] = fp8(v_p[c]) | fp8(v_{p+1}[c])<<8, p in {0,1,2}.
//   layer1 row 64B  -> table 9.6MB (was 19.2 bf16-paired)
//   layer2 row 32B  -> table 4.8MB ~= per-XCD L2 -> mostly resident
// One contiguous wave txn per edge; HW cvt_f32_fp8 decode. Root/self path
// stays fp32 so only the deg-averaged message carries fp8 noise.
// Everything else identical to R10 (bucket-sort CSR, LDS-staged xw, wave-
// per-node agg with in-wave softmax).

#define F_IN   48
#define HID    32
#define NCLS   10
#define KS     4
#define BKT_SH 8               // 256 nodes per bucket
#define TILE   4096            // edges per bucket_scatter block

__device__ inline unsigned short f2bf(float f) {
    unsigned x = __float_as_uint(f);
    unsigned r = x + 0x7FFFu + ((x >> 16) & 1u);  // RNE
    return (unsigned short)(r >> 16);
}
__device__ inline float bf2f(unsigned short u) {
    return __uint_as_float(((unsigned)u) << 16);
}
__device__ inline unsigned fp8e(float f) {
    __hip_fp8_e4m3 v(f);
    return (unsigned)v.__x;
}
__device__ inline float fp8d(unsigned byte) {
    __hip_fp8_e4m3 v;
    v.__x = (__hip_fp8_storage_t)byte;
    return (float)v;
}

// ---------- CSR build ----------

__global__ void bucket_hist_kernel(const int* __restrict__ ei, int* __restrict__ bcnt,
                                   int E, int NB) {
    __shared__ int lcnt[256];
    int t = threadIdx.x;
    lcnt[t] = 0;
    __syncthreads();
    int e0 = blockIdx.x * TILE;
    int n = min(TILE, E - e0);
    for (int r = 0; r < TILE / 256; ++r) {
        int i = r * 256 + t;
        if (i < n) atomicAdd(&lcnt[ei[E + e0 + i] >> BKT_SH], 1);
    }
    __syncthreads();
    if (t < NB && lcnt[t] > 0) atomicAdd(&bcnt[t], lcnt[t]);
}

__global__ void mini_scan_kernel(const int* __restrict__ bcnt, int* __restrict__ bbase,
                                 int* __restrict__ gcur, int NB) {
    __shared__ int a[256], c[256];
    int t = threadIdx.x;
    int v = (t < NB) ? bcnt[t] : 0;
    a[t] = v; c[t] = v;
    __syncthreads();
    for (int o = 1; o < 256; o <<= 1) {
        int w = (t >= o) ? a[t - o] : 0;
        __syncthreads();
        a[t] += w;
        __syncthreads();
    }
    int ex = a[t] - c[t];
    if (t < NB) { bbase[t] = ex; gcur[t] = ex; }
    if (t == 0) bbase[NB] = a[255];
}

__global__ void bucket_scatter_kernel(const int* __restrict__ ei, const float* __restrict__ ea,
                                      int* __restrict__ gcur, uint2* __restrict__ tpd,
                                      int E, int NB) {
    __shared__ unsigned spl[TILE];
    __shared__ unsigned short sdst[TILE];
    __shared__ unsigned short inv[TILE];
    __shared__ int lcnt[256], loff[256], lrank[256], gb[256];
    int t = threadIdx.x;
    lcnt[t] = 0; lrank[t] = 0;
    __syncthreads();
    int e0 = blockIdx.x * TILE;
    int n = min(TILE, E - e0);
    for (int r = 0; r < TILE / 256; ++r) {
        int i = r * 256 + t;
        if (i < n) {
            int e = e0 + i;
            int src = ei[e];
            int dst = ei[E + e];
            float u = ea[e];
            float v = u * (float)(KS - 1);
            float vf = floorf(v);
            int k0 = min(max((int)vf, 0), 2);          // clamp to 2 (pair id)
            float fr = v - (float)k0;
            unsigned qf = (unsigned)(fr * 16383.f + 0.5f);  // 14-bit frac
            spl[i] = (unsigned)(src * 3 + k0) | (qf << 18);
            sdst[i] = (unsigned short)dst;
            atomicAdd(&lcnt[dst >> BKT_SH], 1);
        }
    }
    __syncthreads();
    loff[t] = lcnt[t];
    __syncthreads();
    for (int o = 1; o < 256; o <<= 1) {
        int w = (t >= o) ? loff[t - o] : 0;
        __syncthreads();
        loff[t] += w;
        __syncthreads();
    }
    int ex = loff[t] - lcnt[t];
    __syncthreads();
    loff[t] = ex;
    if (t < NB) gb[t] = atomicAdd(&gcur[t], lcnt[t]);
    __syncthreads();
    for (int r = 0; r < TILE / 256; ++r) {
        int i = r * 256 + t;
        if (i < n) {
            int b = sdst[i] >> BKT_SH;
            int p = loff[b] + atomicAdd(&lrank[b], 1);
            inv[p] = (unsigned short)i;
        }
    }
    __syncthreads();
    for (int r = 0; r < TILE / 256; ++r) {
        int j = r * 256 + t;
        if (j < n) {
            int i = inv[j];
            int d = sdst[i];
            int b = d >> BKT_SH;
            int pos = gb[b] + (j - loff[b]);
            tpd[pos] = make_uint2(spl[i], (unsigned)d);
        }
    }
}

__global__ void node_sort_kernel(const uint2* __restrict__ tpd, const int* __restrict__ bbase,
                                 unsigned* __restrict__ spk, int* __restrict__ offs,
                                 int N, int NB) {
    __shared__ int hc[256], hs[256], hr[256];
    int b = blockIdx.x;
    int t = threadIdx.x;
    int nb0 = b << BKT_SH;
    int nb = min(256, N - nb0);
    int base = bbase[b];
    int m = bbase[b + 1] - base;
    hc[t] = 0; hr[t] = 0;
    __syncthreads();
    for (int i = t; i < m; i += 256) atomicAdd(&hc[tpd[base + i].y - nb0], 1);
    __syncthreads();
    hs[t] = hc[t];
    __syncthreads();
    for (int o = 1; o < 256; o <<= 1) {
        int w = (t >= o) ? hs[t - o] : 0;
        __syncthreads();
        hs[t] += w;
        __syncthreads();
    }
    if (t < nb) offs[nb0 + t] = base + (hs[t] - hc[t]);
    if (b == NB - 1 && t == 0) offs[N] = base + m;
    for (int i = t; i < m; i += 256) {
        uint2 rec = tpd[base + i];
        int d = rec.y - nb0;
        int p = (hs[d] - hc[d]) + atomicAdd(&hr[d], 1);
        spk[base + p] = rec.x;
    }
}

// ---------- xw tables (LDS-staged W; plain bf16 layouts, unchanged) ----------

__global__ __launch_bounds__(320) void xw1_kernel(
        const float* __restrict__ X, const float* __restrict__ W,
        const float* __restrict__ R, unsigned short* __restrict__ outk,
        float* __restrict__ outr, int n) {
    __shared__ float lw[48 * 160];
    int t = threadIdx.x;
    for (int i = t; i < 48 * 160; i += 320) {
        int f = i / 160;
        int col = i - f * 160;
        lw[i] = (col < 128) ? W[(size_t)(col >> 5) * (48 * 32) + f * 32 + (col & 31)]
                            : R[f * 32 + (col - 128)];
    }
    __syncthreads();
    int g = t % 40;      // colgroup (4 cols)
    int lp = t / 40;     // local pair 0..7
    int n0 = (blockIdx.x * 8 + lp) * 2;
    if (n0 + 1 >= n) return;
    const float4* X0 = (const float4*)(X + (size_t)n0 * F_IN);
    const float4* X1 = (const float4*)(X + (size_t)(n0 + 1) * F_IN);
    float4 x0[12], x1[12];
#pragma unroll
    for (int i = 0; i < 12; ++i) { x0[i] = X0[i]; x1[i] = X1[i]; }
    const float4* lw4 = (const float4*)lw;  // lw4[f*40 + g]
    float4 a0 = {0,0,0,0}, a1 = {0,0,0,0};
#pragma unroll
    for (int fb = 0; fb < 12; ++fb) {
        float4 v0 = x0[fb], v1 = x1[fb];
#pragma unroll
        for (int j = 0; j < 4; ++j) {
            float s0 = (j == 0) ? v0.x : (j == 1) ? v0.y : (j == 2) ? v0.z : v0.w;
            float s1 = (j == 0) ? v1.x : (j == 1) ? v1.y : (j == 2) ? v1.z : v1.w;
            float4 w = lw4[(fb * 4 + j) * 40 + g];
            a0.x = fmaf(s0, w.x, a0.x); a0.y = fmaf(s0, w.y, a0.y);
            a0.z = fmaf(s0, w.z, a0.z); a0.w = fmaf(s0, w.w, a0.w);
            a1.x = fmaf(s1, w.x, a1.x); a1.y = fmaf(s1, w.y, a1.y);
            a1.z = fmaf(s1, w.z, a1.z); a1.w = fmaf(s1, w.w, a1.w);
        }
    }
    if (g < 32) {  // plain [node][k][32c] bf16
        uint2 u0, u1;
        u0.x = f2bf(a0.x) | ((unsigned)f2bf(a0.y) << 16);
        u0.y = f2bf(a0.z) | ((unsigned)f2bf(a0.w) << 16);
        u1.x = f2bf(a1.x) | ((unsigned)f2bf(a1.y) << 16);
        u1.y = f2bf(a1.z) | ((unsigned)f2bf(a1.w) << 16);
        *(uint2*)(outk + (size_t)n0 * (KS * HID) + g * 4) = u0;
        *(uint2*)(outk + (size_t)(n0 + 1) * (KS * HID) + g * 4) = u1;
    } else {
        int o = 4 * g - 128;
        *(float4*)(outr + (size_t)n0 * HID + o) = a0;
        *(float4*)(outr + (size_t)(n0 + 1) * HID + o) = a1;
    }
}

__global__ void xw2_kernel(const float* __restrict__ H, const float* __restrict__ W,
                           const float* __restrict__ R, unsigned short* __restrict__ outk,
                           float* __restrict__ outr, int n) {
    __shared__ float lw2[32 * 50];
    int t = threadIdx.x;
    for (int i = t; i < 32 * 50; i += 256) {
        int f = i / 50;
        int col = i - f * 50;
        lw2[i] = (col < 40) ? W[(size_t)(col / 10) * (32 * 10) + f * 10 + (col % 10)]
                            : R[f * 10 + (col - 40)];
    }
    __syncthreads();
    int total = (n / 2) * 25;
    int id = blockIdx.x * blockDim.x + t;
    if (id >= total) return;
    int p = id % 25;
    int pr = id / 25;
    int n0 = 2 * pr;
    const float4* H0 = (const float4*)(H + (size_t)n0 * HID);
    const float4* H1 = (const float4*)(H + (size_t)(n0 + 1) * HID);
    float4 h0[8], h1[8];
#pragma unroll
    for (int i = 0; i < 8; ++i) { h0[i] = H0[i]; h1[i] = H1[i]; }
    const float2* lwp = (const float2*)lw2;  // lwp[f*25 + p]
    float ax0 = 0.f, ay0 = 0.f, ax1 = 0.f, ay1 = 0.f;
#pragma unroll
    for (int fb = 0; fb < 8; ++fb) {
        float4 v0 = h0[fb], v1 = h1[fb];
#pragma unroll
        for (int j = 0; j < 4; ++j) {
            float s0 = (j == 0) ? v0.x : (j == 1) ? v0.y : (j == 2) ? v0.z : v0.w;
            float s1 = (j == 0) ? v1.x : (j == 1) ? v1.y : (j == 2) ? v1.z : v1.w;
            float2 w = lwp[(fb * 4 + j) * 25 + p];
            ax0 = fmaf(s0, w.x, ax0); ay0 = fmaf(s0, w.y, ay0);
            ax1 = fmaf(s1, w.x, ax1); ay1 = fmaf(s1, w.y, ay1);
        }
    }
    int col = 2 * p;
    if (col < 40) {           // plain [node][k][16c] bf16 (10..15 unused)
        int k = col / 10;
        int o = col - k * 10;
        *(unsigned*)(outk + (size_t)n0 * 64 + k * 16 + o) =
            f2bf(ax0) | ((unsigned)f2bf(ay0) << 16);
        *(unsigned*)(outk + (size_t)(n0 + 1) * 64 + k * 16 + o) =
            f2bf(ax1) | ((unsigned)f2bf(ay1) << 16);
    } else {
        int o = col - 40;
        *(float2*)(outr + (size_t)n0 * NCLS + o) = make_float2(ax0, ay0);
        *(float2*)(outr + (size_t)(n0 + 1) * NCLS + o) = make_float2(ax1, ay1);
    }
}

// ---------- pairify: plain bf16 -> fp8 pair-interleaved (ushort) ----------

// Layer1: out[node*96 + p*32 + c] = fp8(in[n*128+p*32+c]) | fp8(in[..+32+c])<<8
__global__ void pairify1_kernel(const unsigned short* __restrict__ in,
                                unsigned short* __restrict__ out, int total) {
    int id = blockIdx.x * 256 + threadIdx.x;
    if (id >= total) return;
    int c = id & 31;
    int rest = id >> 5;        // node*3 + p
    int node = rest / 3;
    int ib = (rest + node) * 32 + c;   // node*128 + p*32 + c
    unsigned lo = fp8e(bf2f(in[ib]));
    unsigned hi = fp8e(bf2f(in[ib + 32]));
    out[id] = (unsigned short)(lo | (hi << 8));
}

// Layer2: out[node*48 + p*16 + c] = fp8(in[n*64+p*16+c]) | fp8(in[..+16+c])<<8
__global__ void pairify2_kernel(const unsigned short* __restrict__ in,
                                unsigned short* __restrict__ out, int total) {
    int id = blockIdx.x * 256 + threadIdx.x;
    if (id >= total) return;
    int c = id & 15;
    int rest = id >> 4;        // node*3 + p
    int node = rest / 3;
    int ib = (rest + node) * 16 + c;   // node*64 + p*16 + c
    unsigned lo = fp8e(bf2f(in[ib]));
    unsigned hi = fp8e(bf2f(in[ib + 16]));
    out[id] = (unsigned short)(lo | (hi << 8));
}

// ---------- aggregation (wave per node, fp8-paired gathers) ----------

__device__ inline float ginterp(const unsigned short* __restrict__ t, unsigned p, int rowlen) {
    unsigned w = t[(p & 0x3FFFFu) * rowlen];
    float v0 = fp8d(w & 0xFFu);
    float v1 = fp8d(w >> 8);
    return fmaf((float)(p >> 18) * (1.f / 16383.f), v1 - v0, v0);
}

// Wave = node; lanes = 2 halves x 32 ch; 4-deep unroll = 8 loads in flight.
// Row = 32 ushorts = 64B (one line per edge).
__global__ void agg1_kernel(const unsigned short* __restrict__ tbl, const float* __restrict__ xr,
                            const int* __restrict__ offs, const unsigned* __restrict__ spk,
                            const float* __restrict__ bias, float* __restrict__ h, int n) {
    int lane = threadIdx.x & 63;
    int c = lane & 31;
    int half = lane >> 5;
    int node = blockIdx.x * 4 + (threadIdx.x >> 6);
    if (node >= n) return;
    int beg = offs[node], end = offs[node + 1];
    const unsigned short* t = tbl + c;
    float s0 = 0.f, s1 = 0.f, s2 = 0.f, s3 = 0.f;
    int e = beg + half;
    for (; e + 6 < end; e += 8) {
        unsigned p0 = __builtin_nontemporal_load(spk + e);
        unsigned p1 = __builtin_nontemporal_load(spk + e + 2);
        unsigned p2 = __builtin_nontemporal_load(spk + e + 4);
        unsigned p3 = __builtin_nontemporal_load(spk + e + 6);
        s0 += ginterp(t, p0, 32);
        s1 += ginterp(t, p1, 32);
        s2 += ginterp(t, p2, 32);
        s3 += ginterp(t, p3, 32);
    }
    for (; e < end; e += 2)
        s0 += ginterp(t, __builtin_nontemporal_load(spk + e), 32);
    float sum = (s0 + s1) + (s2 + s3);
    sum += __shfl_xor(sum, 32, 64);  // merge halves
    if (half == 0) {
        int deg = end - beg;
        float m = sum / (float)(deg > 0 ? deg : 1);
        float o = m + xr[(size_t)node * HID + c] + bias[c];
        h[(size_t)node * HID + c] = (o > 0.f) ? o : expm1f(o);
    }
}

// Wave = node; lanes = 4 slots x 16 ch; 2x unroll = 8 loads in flight.
// Row = 16 ushorts = 32B; table 4.8MB ~ L2-resident. In-wave log_softmax.
__global__ void agg2_kernel(const unsigned short* __restrict__ tbl, const float* __restrict__ xr,
                            const int* __restrict__ offs, const unsigned* __restrict__ spk,
                            const float* __restrict__ bias, float* __restrict__ out, int n) {
    int lane = threadIdx.x & 63;
    int c = lane & 15;
    int slot = lane >> 4;
    int node = blockIdx.x * 4 + (threadIdx.x >> 6);
    if (node >= n) return;
    int beg = offs[node], end = offs[node + 1];
    const unsigned short* t = tbl + c;
    float s0 = 0.f, s1 = 0.f;
    int e = beg + slot;
    for (; e + 4 < end; e += 8) {
        unsigned p0 = __builtin_nontemporal_load(spk + e);
        unsigned p1 = __builtin_nontemporal_load(spk + e + 4);
        s0 += ginterp(t, p0, 16);
        s1 += ginterp(t, p1, 16);
    }
    if (e < end) s0 += ginterp(t, __builtin_nontemporal_load(spk + e), 16);
    float sum = s0 + s1;
    sum += __shfl_xor(sum, 16, 64);
    sum += __shfl_xor(sum, 32, 64);  // all lanes: channel-c total
    int deg = end - beg;
    float m = sum / (float)(deg > 0 ? deg : 1);
    int cc = min(c, NCLS - 1);
    float logit = m + xr[(size_t)node * NCLS + cc] + bias[cc];
    bool active = (c < NCLS);
    float mx = active ? logit : -INFINITY;
#pragma unroll
    for (int msk = 1; msk < 16; msk <<= 1) mx = fmaxf(mx, __shfl_xor(mx, msk, 16));
    float ex = active ? expf(logit - mx) : 0.f;
    float s = ex;
#pragma unroll
    for (int msk = 1; msk < 16; msk <<= 1) s += __shfl_xor(s, msk, 16);
    if (active && slot == 0) out[(size_t)node * NCLS + c] = (logit - mx) - logf(s);
}

extern "C" void kernel_launch(void* const* d_in, const int* in_sizes, int n_in,
                              void* d_out, int out_size, void* d_ws, size_t ws_size,
                              hipStream_t stream) {
    const float* x       = (const float*)d_in[0];
    const int*   ei      = (const int*)d_in[1];
    const float* ea      = (const float*)d_in[2];
    const float* W1      = (const float*)d_in[3];
    const float* root1   = (const float*)d_in[4];
    const float* bias1   = (const float*)d_in[5];
    const float* W2      = (const float*)d_in[6];
    const float* root2   = (const float*)d_in[7];
    const float* bias2   = (const float*)d_in[8];
    float* out = (float*)d_out;

    const int N = in_sizes[0] / F_IN;      // 50000
    const int E = in_sizes[2];             // 1600000
    const int NB = (N + 255) >> BKT_SH;    // 196

    char* base = (char*)d_ws;
    size_t off = 0;
    auto alloc = [&](size_t bytes) {
        char* p = base + off;
        off = (off + bytes + 255) & ~(size_t)255;
        return (void*)p;
    };
    unsigned short* xwk1p = (unsigned short*)alloc((size_t)N * 128 * 2);  // 12.8 MB plain bf16
    unsigned short* xwk1  = (unsigned short*)alloc((size_t)N * 96 * 2);   // 9.6 MB fp8-paired
    float* xr1            = (float*)alloc((size_t)N * HID * 4);           // 6.4 MB
    float* h              = (float*)alloc((size_t)N * HID * 4);           // 6.4 MB
    float* xr2            = (float*)alloc((size_t)N * NCLS * 4);          // 2.0 MB
    int* offs             = (int*)alloc(((size_t)N + 1) * 4);
    int* bcnt             = (int*)alloc((size_t)NB * 4);
    int* bbase            = (int*)alloc(((size_t)NB + 1) * 4);
    int* gcur             = (int*)alloc((size_t)NB * 4);
    unsigned* spk         = (unsigned*)alloc((size_t)E * 4);              // 6.4 MB
    uint2* tpd            = (uint2*)xwk1p;   // 12.8 MB alias (dead before xw1)
    unsigned short* xwk2p = xwk1p;           // N*64 ush alias (xwk1p dead after pairify1)
    unsigned short* xwk2  = xwk1;            // N*48 ush alias (xwk1 dead after agg1)
    if (ws_size < off) return;

    int ebk = (E + TILE - 1) / TILE;

    hipMemsetAsync(bcnt, 0, (size_t)NB * 4, stream);
    bucket_hist_kernel<<<ebk, 256, 0, stream>>>(ei, bcnt, E, NB);
    mini_scan_kernel<<<1, 256, 0, stream>>>(bcnt, bbase, gcur, NB);
    bucket_scatter_kernel<<<ebk, 256, 0, stream>>>(ei, ea, gcur, tpd, E, NB);
    node_sort_kernel<<<NB, 256, 0, stream>>>(tpd, bbase, spk, offs, N, NB);
    // xw1 after node_sort (tpd aliases xwk1p)
    xw1_kernel<<<(N + 15) / 16, 320, 0, stream>>>(x, W1, root1, xwk1p, xr1, N);
    pairify1_kernel<<<(N * 96 + 255) / 256, 256, 0, stream>>>(xwk1p, xwk1, N * 96);
    agg1_kernel<<<(N + 3) / 4, 256, 0, stream>>>(xwk1, xr1, offs, spk, bias1, h, N);
    {
        int total = (N / 2) * 25;
        xw2_kernel<<<(total + 255) / 256, 256, 0, stream>>>(h, W2, root2, xwk2p, xr2, N);
    }
    pairify2_kernel<<<(N * 48 + 255) / 256, 256, 0, stream>>>(xwk2p, xwk2, N * 48);
    agg2_kernel<<<(N + 3) / 4, 256, 0, stream>>>(xwk2, xr2, offs, spk, bias2, out, N);
}